// Round 1
// baseline (1226.211 us; speedup 1.0000x reference)
//
#include <hip/hip_runtime.h>
#include <math.h>

#define N_NODES 50000
#define N_EDGES 800000
#define ND 128
#define ED 64
#define TD 16
#define OD 128
#define NH 4
#define INDIM 208   // ND+ED+TD
#define K2DIM 336   // INDIM + ND

#define PREAGG_STRIDE 212
#define OFF_PREAGG 0ll
#define OFF_EXPL   10600000ll
#define OFF_DENOM  13800000ll
#define OFF_SPG    13800016ll
#define OFF_WFUSE  13800032ll
#define OFF_BFUSE  13800864ll
#define OFF_WMO    13800880ll
#define OFF_BMO    13827504ll
#define WS_FLOATS  13827632ll

// ---------------- K0: fold weights ----------------
// Wmo = Wm @ Wo_top (208x128), Wfuse = Wm @ Wa_top (208x4),
// bfuse = bm@Wa_top + ba, bmo = bm@Wo_top, spg = softplus(gammas)
__global__ void k0_prep(const float* __restrict__ Wm, const float* __restrict__ bm,
                        const float* __restrict__ Wa, const float* __restrict__ ba,
                        const float* __restrict__ Wo, const float* __restrict__ gammas,
                        float* __restrict__ ws) {
  int b = blockIdx.x, j = threadIdx.x;
  if (b < INDIM) {
    float acc = 0.f;
    for (int m = 0; m < OD; ++m) acc += Wm[b * OD + m] * Wo[m * OD + j];
    ws[OFF_WMO + (long)b * OD + j] = acc;
    if (j < NH) {
      float a = 0.f;
      for (int m = 0; m < OD; ++m) a += Wm[b * OD + m] * Wa[m * NH + j];
      ws[OFF_WFUSE + (long)b * NH + j] = a;
    }
  } else {
    if (j < TD) ws[OFF_SPG + j] = log1pf(expf(gammas[j]));
    if (j < NH) {
      float a = ba[j];
      for (int m = 0; m < OD; ++m) a += bm[m] * Wa[m * NH + j];
      ws[OFF_BFUSE + j] = a;
    }
    float a2 = 0.f;
    for (int m = 0; m < OD; ++m) a2 += bm[m] * Wo[m * OD + j];
    ws[OFF_BMO + j] = a2;
  }
}

// ---------------- K1: edge logits + exp + denominator ----------------
// one wave (64 lanes) per edge, grid-stride
__global__ __launch_bounds__(256) void k1_logits(
    const float* __restrict__ x, const int* __restrict__ ei,
    const float* __restrict__ ef, const float* __restrict__ td,
    const float* __restrict__ Wa, float* __restrict__ ws) {
  __shared__ float wf[INDIM * NH];   // 832
  __shared__ float wab[ND * NH];     // 512
  __shared__ float spg[TD];
  __shared__ float bf[NH];
  __shared__ float part[NH];
  int tid = threadIdx.x;
  for (int i = tid; i < INDIM * NH; i += 256) wf[i] = ws[OFF_WFUSE + i];
  for (int i = tid; i < ND * NH; i += 256) wab[i] = Wa[ND * NH + i];
  if (tid < TD) spg[tid] = ws[OFF_SPG + tid];
  if (tid < NH) { bf[tid] = ws[OFF_BFUSE + tid]; part[tid] = 0.f; }
  __syncthreads();

  int lane = tid & 63;
  long wid = ((long)blockIdx.x * 256 + tid) >> 6;
  long nw = ((long)gridDim.x * 256) >> 6;
  float* expl = ws + OFF_EXPL;

  for (long e = wid; e < N_EDGES; e += nw) {
    int s = ei[e], d = ei[N_EDGES + e];
    float a0 = 0.f, a1 = 0.f, a2 = 0.f, a3 = 0.f;
    float v; int k;
#define ACCW(vv, kk, W) { float _v = (vv); const float* _w = &W[(kk) * 4]; \
    a0 += _v * _w[0]; a1 += _v * _w[1]; a2 += _v * _w[2]; a3 += _v * _w[3]; }
    v = x[(long)s * ND + lane];        ACCW(v, lane, wf);
    v = x[(long)s * ND + 64 + lane];   ACCW(v, 64 + lane, wf);
    v = ef[(long)e * ED + lane];       ACCW(v, 128 + lane, wf);
    if (lane < TD) {
      float dt = fmaxf(td[e], 0.f);
      float te = expf(-spg[lane] * dt);
      ACCW(te, 192 + lane, wf);
    }
    v = x[(long)d * ND + lane];        ACCW(v, lane, wab);
    v = x[(long)d * ND + 64 + lane];   ACCW(v, 64 + lane, wab);
#undef ACCW
    for (int off = 32; off; off >>= 1) {
      a0 += __shfl_xor(a0, off);
      a1 += __shfl_xor(a1, off);
      a2 += __shfl_xor(a2, off);
      a3 += __shfl_xor(a3, off);
    }
    if (lane == 0) {
      float e0 = expf(a0 + bf[0]), e1 = expf(a1 + bf[1]);
      float e2 = expf(a2 + bf[2]), e3 = expf(a3 + bf[3]);
      reinterpret_cast<float4*>(expl)[e] = make_float4(e0, e1, e2, e3);
      atomicAdd(&part[0], e0); atomicAdd(&part[1], e1);
      atomicAdd(&part[2], e2); atomicAdd(&part[3], e3);
    }
  }
  __syncthreads();
  if (tid < NH) atomicAdd(&ws[OFF_DENOM + tid], part[tid]);
}

// ---------------- K3: weighted scatter of 208-dim inputs ----------------
__global__ __launch_bounds__(256) void k3_scatter(
    const float* __restrict__ x, const int* __restrict__ ei,
    const float* __restrict__ ef, const float* __restrict__ td,
    float* __restrict__ ws) {
  __shared__ float inv[NH];
  __shared__ float spg[TD];
  int tid = threadIdx.x;
  if (tid < NH) inv[tid] = 1.f / ws[OFF_DENOM + tid];
  if (tid < TD) spg[tid] = ws[OFF_SPG + tid];
  __syncthreads();

  int lane = tid & 63;
  long wid = ((long)blockIdx.x * 256 + tid) >> 6;
  long nw = ((long)gridDim.x * 256) >> 6;
  const float4* expl = reinterpret_cast<const float4*>(ws + OFF_EXPL);
  float* pre = ws + OFF_PREAGG;

  for (long e = wid; e < N_EDGES; e += nw) {
    int s = ei[e], d = ei[N_EDGES + e];
    float4 ev = expl[e];
    float w = 0.25f * (ev.x * inv[0] + ev.y * inv[1] + ev.z * inv[2] + ev.w * inv[3]);
    float* pr = pre + (long)d * PREAGG_STRIDE;
    unsafeAtomicAdd(pr + lane,        w * x[(long)s * ND + lane]);
    unsafeAtomicAdd(pr + 64 + lane,   w * x[(long)s * ND + 64 + lane]);
    unsafeAtomicAdd(pr + 128 + lane,  w * ef[(long)e * ED + lane]);
    if (lane < TD) {
      float dt = fmaxf(td[e], 0.f);
      unsafeAtomicAdd(pr + 192 + lane, w * expf(-spg[lane] * dt));
    }
    if (lane == 0) unsafeAtomicAdd(pr + 208, w);
  }
}

// ---------------- K4: node MLP (336x128) + GELU + LayerNorm ----------------
__global__ __launch_bounds__(256) void k4_out(
    const float* __restrict__ x, const float* __restrict__ Wo,
    const float* __restrict__ bo, const float* __restrict__ lng,
    const float* __restrict__ lnb, const float* __restrict__ ws,
    float* __restrict__ out) {
  __shared__ float inL[8][K2DIM + 1];  // 337: [0,208) pre_agg, [208,336) x, [336] sum_w
  __shared__ float hL[8][OD];
  int tid = threadIdx.x;
  long node0 = (long)blockIdx.x * 8;
  const float* pre = ws + OFF_PREAGG;

  for (int idx = tid; idx < 8 * (K2DIM + 1); idx += 256) {
    int n = idx / (K2DIM + 1);
    int k = idx - n * (K2DIM + 1);
    long nn = node0 + n;
    float v;
    if (k < INDIM)      v = pre[nn * PREAGG_STRIDE + k];
    else if (k < K2DIM) v = x[nn * ND + (k - INDIM)];
    else                v = pre[nn * PREAGG_STRIDE + INDIM];
    inL[n][k] = v;
  }
  __syncthreads();

  int j = tid & 127;
  int p = tid >> 7;          // pair p handles nodes {p, p+2, p+4, p+6}
  float acc0 = 0.f, acc1 = 0.f, acc2 = 0.f, acc3 = 0.f;
  const float* wmo = ws + OFF_WMO;
#pragma unroll 4
  for (int k = 0; k < INDIM; ++k) {
    float w = wmo[k * OD + j];
    acc0 += w * inL[p + 0][k];
    acc1 += w * inL[p + 2][k];
    acc2 += w * inL[p + 4][k];
    acc3 += w * inL[p + 6][k];
  }
  const float* wob = Wo + OD * OD;  // rows 128..255 of Wo (the x part)
#pragma unroll 4
  for (int k = 0; k < ND; ++k) {
    float w = wob[k * OD + j];
    acc0 += w * inL[p + 0][INDIM + k];
    acc1 += w * inL[p + 2][INDIM + k];
    acc2 += w * inL[p + 4][INDIM + k];
    acc3 += w * inL[p + 6][INDIM + k];
  }
  float bj = bo[j], bmj = ws[OFF_BMO + j];
  {
    float a;
    a = acc0 + bj + inL[p + 0][K2DIM] * bmj;
    hL[p + 0][j] = 0.5f * a * (1.f + erff(a * 0.70710678118654752f));
    a = acc1 + bj + inL[p + 2][K2DIM] * bmj;
    hL[p + 2][j] = 0.5f * a * (1.f + erff(a * 0.70710678118654752f));
    a = acc2 + bj + inL[p + 4][K2DIM] * bmj;
    hL[p + 4][j] = 0.5f * a * (1.f + erff(a * 0.70710678118654752f));
    a = acc3 + bj + inL[p + 6][K2DIM] * bmj;
    hL[p + 6][j] = 0.5f * a * (1.f + erff(a * 0.70710678118654752f));
  }
  __syncthreads();

  int wv = tid >> 6, lane = tid & 63;
  for (int t = 0; t < 2; ++t) {
    int n = wv * 2 + t;
    float v0 = hL[n][lane], v1 = hL[n][64 + lane];
    float s = v0 + v1, s2 = v0 * v0 + v1 * v1;
    for (int off = 32; off; off >>= 1) {
      s  += __shfl_xor(s, off);
      s2 += __shfl_xor(s2, off);
    }
    float mu = s * (1.f / OD);
    float var = s2 * (1.f / OD) - mu * mu;
    float rstd = rsqrtf(var + 1e-5f);
    long nn = node0 + n;
    out[nn * OD + lane]      = (v0 - mu) * rstd * lng[lane] + lnb[lane];
    out[nn * OD + 64 + lane] = (v1 - mu) * rstd * lng[64 + lane] + lnb[64 + lane];
  }
}

extern "C" void kernel_launch(void* const* d_in, const int* in_sizes, int n_in,
                              void* d_out, int out_size, void* d_ws, size_t ws_size,
                              hipStream_t stream) {
  const float* x   = (const float*)d_in[0];
  const int*   ei  = (const int*)d_in[1];
  const float* ef  = (const float*)d_in[2];
  const float* td  = (const float*)d_in[3];
  const float* gm  = (const float*)d_in[4];
  const float* Wm  = (const float*)d_in[5];
  const float* bm  = (const float*)d_in[6];
  const float* Wa  = (const float*)d_in[7];
  const float* ba  = (const float*)d_in[8];
  const float* Wo  = (const float*)d_in[9];
  const float* bo  = (const float*)d_in[10];
  const float* lng = (const float*)d_in[11];
  const float* lnb = (const float*)d_in[12];
  float* ws = (float*)d_ws;
  float* out = (float*)d_out;
  if (ws_size < (size_t)WS_FLOATS * 4) return;

  hipMemsetAsync(ws + OFF_PREAGG, 0, 10600000ll * 4, stream);  // pre_agg
  hipMemsetAsync(ws + OFF_DENOM, 0, 64, stream);               // denominators

  k0_prep<<<INDIM + 1, 128, 0, stream>>>(Wm, bm, Wa, ba, Wo, gm, ws);
  k1_logits<<<4096, 256, 0, stream>>>(x, ei, ef, td, Wa, ws);
  k3_scatter<<<4096, 256, 0, stream>>>(x, ei, ef, td, ws);
  k4_out<<<N_NODES / 8, 256, 0, stream>>>(x, Wo, bo, lng, lnb, ws, out);
}

// Round 2
// 596.178 us; speedup vs baseline: 2.0568x; 2.0568x over previous
//
#include <hip/hip_runtime.h>
#include <math.h>

#define N_NODES 50000
#define N_EDGES 800000
#define ND 128
#define ED 64
#define TD 16
#define OD 128
#define NH 4
#define INDIM 208   // ND+ED+TD
#define K2DIM 336   // INDIM + ND

// workspace layout (float offsets)
#define OFF_EXPL   0ll          // 800000 * 4
#define OFF_DENOM  3200000ll    // 4 (pad 16)
#define OFF_SPG    3200016ll    // 16
#define OFF_WFUSE  3200032ll    // 208*4
#define OFF_BFUSE  3200864ll    // 4 (pad 16)
#define OFF_WMO    3200880ll    // 208*128
#define OFF_BMO    3227504ll    // 128
#define OFF_XS4    3227632ll    // 50000*4
#define OFF_XD4    3427632ll    // 50000*4
#define OFF_CNT    3627632ll    // 50000 ints
#define OFF_START  3677632ll    // 50001 ints (pad to 50016)
#define OFF_CURSOR 3727648ll    // 50000 ints
#define OFF_PERM   3777648ll    // 800000 uint2
#define WS_FLOATS  5377648ll

// ---------------- K0: fold weights ----------------
// Wmo = Wm @ Wo_top (208x128), Wfuse = Wm @ Wa_top (208x4),
// bfuse = bm@Wa_top + ba, bmo = bm@Wo_top, spg = softplus(gammas)
__global__ void k0_prep(const float* __restrict__ Wm, const float* __restrict__ bm,
                        const float* __restrict__ Wa, const float* __restrict__ ba,
                        const float* __restrict__ Wo, const float* __restrict__ gammas,
                        float* __restrict__ ws) {
  int b = blockIdx.x, j = threadIdx.x;
  if (b < INDIM) {
    float acc = 0.f;
    for (int m = 0; m < OD; ++m) acc += Wm[b * OD + m] * Wo[m * OD + j];
    ws[OFF_WMO + (long)b * OD + j] = acc;
    if (j < NH) {
      float a = 0.f;
      for (int m = 0; m < OD; ++m) a += Wm[b * OD + m] * Wa[m * NH + j];
      ws[OFF_WFUSE + (long)b * NH + j] = a;
    }
  } else {
    if (j < TD) ws[OFF_SPG + j] = log1pf(expf(gammas[j]));
    if (j < NH) {
      float a = ba[j];
      for (int m = 0; m < OD; ++m) a += bm[m] * Wa[m * NH + j];
      ws[OFF_BFUSE + j] = a;
    }
    float a2 = 0.f;
    for (int m = 0; m < OD; ++m) a2 += bm[m] * Wo[m * OD + j];
    ws[OFF_BMO + j] = a2;
  }
}

// ---------------- K0b: per-node 4-dim projections ----------------
// xs4[n][h] = sum_k x[n][k] * Wfuse[k][h]  (k<128 rows of fused Wm@Wa_top)
// xd4[n][h] = sum_k x[n][k] * Wa[128+k][h]
__global__ __launch_bounds__(256) void k0b_nodeproj(
    const float* __restrict__ x, const float* __restrict__ Wa,
    float* __restrict__ ws) {
  __shared__ float wf[ND * NH];
  __shared__ float wab[ND * NH];
  int tid = threadIdx.x;
  for (int i = tid; i < ND * NH; i += 256) { wf[i] = ws[OFF_WFUSE + i]; wab[i] = Wa[ND * NH + i]; }
  __syncthreads();
  int lane = tid & 63, wv = tid >> 6;
  long n = (long)blockIdx.x * 4 + wv;
  if (n >= N_NODES) return;
  float v0 = x[n * ND + lane], v1 = x[n * ND + 64 + lane];
  float s0, s1, s2, s3, d0, d1, d2, d3;
  s0 = v0 * wf[lane * 4 + 0] + v1 * wf[(64 + lane) * 4 + 0];
  s1 = v0 * wf[lane * 4 + 1] + v1 * wf[(64 + lane) * 4 + 1];
  s2 = v0 * wf[lane * 4 + 2] + v1 * wf[(64 + lane) * 4 + 2];
  s3 = v0 * wf[lane * 4 + 3] + v1 * wf[(64 + lane) * 4 + 3];
  d0 = v0 * wab[lane * 4 + 0] + v1 * wab[(64 + lane) * 4 + 0];
  d1 = v0 * wab[lane * 4 + 1] + v1 * wab[(64 + lane) * 4 + 1];
  d2 = v0 * wab[lane * 4 + 2] + v1 * wab[(64 + lane) * 4 + 2];
  d3 = v0 * wab[lane * 4 + 3] + v1 * wab[(64 + lane) * 4 + 3];
  for (int off = 32; off; off >>= 1) {
    s0 += __shfl_xor(s0, off); s1 += __shfl_xor(s1, off);
    s2 += __shfl_xor(s2, off); s3 += __shfl_xor(s3, off);
    d0 += __shfl_xor(d0, off); d1 += __shfl_xor(d1, off);
    d2 += __shfl_xor(d2, off); d3 += __shfl_xor(d3, off);
  }
  if (lane == 0) {
    reinterpret_cast<float4*>(ws + OFF_XS4)[n] = make_float4(s0, s1, s2, s3);
    reinterpret_cast<float4*>(ws + OFF_XD4)[n] = make_float4(d0, d1, d2, d3);
  }
}

// ---------------- K1: edge logits + exp + denominator + dst histogram ----------------
// 16 lanes per edge
__global__ __launch_bounds__(256) void k1_logits(
    const int* __restrict__ ei, const float* __restrict__ ef,
    const float* __restrict__ td, float* __restrict__ ws) {
  __shared__ float wef[ED * NH];   // Wfuse rows 128..191
  __shared__ float wte[TD * NH];   // Wfuse rows 192..207
  __shared__ float bf[NH];
  __shared__ float spg[TD];
  __shared__ float part[NH];
  int tid = threadIdx.x;
  for (int i = tid; i < ED * NH; i += 256) wef[i] = ws[OFF_WFUSE + ND * NH + i];
  if (tid < TD * NH) wte[tid] = ws[OFF_WFUSE + (ND + ED) * NH + tid];
  if (tid < NH) { bf[tid] = ws[OFF_BFUSE + tid]; part[tid] = 0.f; }
  if (tid < TD) spg[tid] = ws[OFF_SPG + tid];
  __syncthreads();

  int r = tid & 15;
  long grp = ((long)blockIdx.x * 256 + tid) >> 4;
  long ngrp = ((long)gridDim.x * 256) >> 4;
  const float4* ef4 = reinterpret_cast<const float4*>(ef);
  float4* expl4 = reinterpret_cast<float4*>(ws + OFF_EXPL);
  const float4* xs4 = reinterpret_cast<const float4*>(ws + OFF_XS4);
  const float4* xd4 = reinterpret_cast<const float4*>(ws + OFF_XD4);
  int* cnt = reinterpret_cast<int*>(ws + OFF_CNT);
  float p0 = 0.f, p1 = 0.f, p2 = 0.f, p3 = 0.f;

  for (long e = grp; e < N_EDGES; e += ngrp) {
    float4 efv = ef4[e * 16 + r];
    const float* w0 = &wef[(4 * r) * 4];
    float a0 = efv.x * w0[0] + efv.y * w0[4] + efv.z * w0[8]  + efv.w * w0[12];
    float a1 = efv.x * w0[1] + efv.y * w0[5] + efv.z * w0[9]  + efv.w * w0[13];
    float a2 = efv.x * w0[2] + efv.y * w0[6] + efv.z * w0[10] + efv.w * w0[14];
    float a3 = efv.x * w0[3] + efv.y * w0[7] + efv.z * w0[11] + efv.w * w0[15];
    float dt = fmaxf(td[e], 0.f);
    float te = expf(-spg[r] * dt);
    a0 += te * wte[r * 4 + 0]; a1 += te * wte[r * 4 + 1];
    a2 += te * wte[r * 4 + 2]; a3 += te * wte[r * 4 + 3];
    for (int off = 8; off; off >>= 1) {
      a0 += __shfl_xor(a0, off); a1 += __shfl_xor(a1, off);
      a2 += __shfl_xor(a2, off); a3 += __shfl_xor(a3, off);
    }
    if (r == 0) {
      int s = ei[e], d = ei[N_EDGES + e];
      float4 xs = xs4[s], xd = xd4[d];
      float e0 = expf(a0 + xs.x + xd.x + bf[0]);
      float e1 = expf(a1 + xs.y + xd.y + bf[1]);
      float e2 = expf(a2 + xs.z + xd.z + bf[2]);
      float e3 = expf(a3 + xs.w + xd.w + bf[3]);
      expl4[e] = make_float4(e0, e1, e2, e3);
      p0 += e0; p1 += e1; p2 += e2; p3 += e3;
      atomicAdd(&cnt[d], 1);
    }
  }
  if ((tid & 15) == 0) {
    atomicAdd(&part[0], p0); atomicAdd(&part[1], p1);
    atomicAdd(&part[2], p2); atomicAdd(&part[3], p3);
  }
  __syncthreads();
  if (tid < NH) atomicAdd(&ws[OFF_DENOM + tid], part[tid]);
}

// ---------------- K2: exclusive scan of counts -> start, cursor ----------------
__global__ void k_scan(float* __restrict__ ws) {
  const int* cnt = reinterpret_cast<const int*>(ws + OFF_CNT);
  int* start = reinterpret_cast<int*>(ws + OFF_START);
  int* cursor = reinterpret_cast<int*>(ws + OFF_CURSOR);
  __shared__ int part[256];
  int tid = threadIdx.x;
  int lo = tid * 196, hi = min(lo + 196, N_NODES);
  int s = 0;
  for (int i = lo; i < hi; ++i) s += cnt[i];
  part[tid] = s;
  __syncthreads();
  if (tid == 0) {
    int run = 0;
    for (int i = 0; i < 256; ++i) { int t = part[i]; part[i] = run; run += t; }
  }
  __syncthreads();
  int run = part[tid];
  for (int i = lo; i < hi; ++i) { start[i] = run; cursor[i] = run; run += cnt[i]; }
  if (tid == 255) start[N_NODES] = run;
}

// ---------------- K3: fill CSR perm with (edge id, weight) ----------------
__global__ __launch_bounds__(256) void k_fill(const int* __restrict__ ei,
                                              float* __restrict__ ws) {
  __shared__ float inv[NH];
  int tid = threadIdx.x;
  if (tid < NH) inv[tid] = 0.25f / ws[OFF_DENOM + tid];
  __syncthreads();
  const float4* expl4 = reinterpret_cast<const float4*>(ws + OFF_EXPL);
  int* cursor = reinterpret_cast<int*>(ws + OFF_CURSOR);
  uint2* perm = reinterpret_cast<uint2*>(ws + OFF_PERM);
  for (long e = (long)blockIdx.x * 256 + tid; e < N_EDGES; e += (long)gridDim.x * 256) {
    int d = ei[N_EDGES + e];
    float4 ev = expl4[e];
    float w = ev.x * inv[0] + ev.y * inv[1] + ev.z * inv[2] + ev.w * inv[3];
    int pos = atomicAdd(&cursor[d], 1);
    uint2 pk; pk.x = (unsigned)e; pk.y = __float_as_uint(w);
    perm[pos] = pk;
  }
}

// ---------------- K4: fused CSR aggregate + MLP + GELU + LayerNorm ----------------
__global__ __launch_bounds__(256) void k4_out(
    const float* __restrict__ x, const int* __restrict__ ei,
    const float* __restrict__ ef, const float* __restrict__ td,
    const float* __restrict__ Wo, const float* __restrict__ bo,
    const float* __restrict__ lng, const float* __restrict__ lnb,
    const float* __restrict__ ws, float* __restrict__ out) {
  __shared__ float inL[8][K2DIM + 1];  // [0,208) agg, [208,336) x, [336] sum_w
  __shared__ float hL[8][OD];
  __shared__ float spg[TD];
  int tid = threadIdx.x;
  long node0 = (long)blockIdx.x * 8;
  if (tid < TD) spg[tid] = ws[OFF_SPG + tid];
  for (int idx = tid; idx < 8 * ND; idx += 256) {
    int n = idx >> 7, k = idx & 127;
    inL[n][INDIM + k] = x[(node0 + n) * ND + k];
  }
  __syncthreads();

  int lane = tid & 63, wv = tid >> 6;
  const int* start = reinterpret_cast<const int*>(ws + OFF_START);
  const uint2* perm = reinterpret_cast<const uint2*>(ws + OFF_PERM);
  for (int t = 0; t < 2; ++t) {
    int nl = wv * 2 + t;
    long n = node0 + nl;
    int i0 = start[n], i1 = start[n + 1];
    float a0 = 0.f, a1 = 0.f, a2 = 0.f, a3 = 0.f, asw = 0.f;
    for (int i = i0; i < i1; ++i) {
      uint2 pk = perm[i];
      int e = (int)pk.x;
      float w = __uint_as_float(pk.y);
      int s = ei[e];
      a0 += w * x[(long)s * ND + lane];
      a1 += w * x[(long)s * ND + 64 + lane];
      a2 += w * ef[(long)e * ED + lane];
      if (lane < TD) a3 += w * expf(-spg[lane] * fmaxf(td[e], 0.f));
      asw += w;
    }
    inL[nl][lane] = a0;
    inL[nl][64 + lane] = a1;
    inL[nl][128 + lane] = a2;
    if (lane < TD) inL[nl][192 + lane] = a3;
    if (lane == 0) inL[nl][K2DIM] = asw;
  }
  __syncthreads();

  int j = tid & 127;
  int p = tid >> 7;          // pair p handles nodes {p, p+2, p+4, p+6}
  float acc0 = 0.f, acc1 = 0.f, acc2 = 0.f, acc3 = 0.f;
  const float* wmo = ws + OFF_WMO;
#pragma unroll 4
  for (int k = 0; k < INDIM; ++k) {
    float w = wmo[k * OD + j];
    acc0 += w * inL[p + 0][k];
    acc1 += w * inL[p + 2][k];
    acc2 += w * inL[p + 4][k];
    acc3 += w * inL[p + 6][k];
  }
  const float* wob = Wo + OD * OD;  // rows 128..255 of Wo (the x part)
#pragma unroll 4
  for (int k = 0; k < ND; ++k) {
    float w = wob[k * OD + j];
    acc0 += w * inL[p + 0][INDIM + k];
    acc1 += w * inL[p + 2][INDIM + k];
    acc2 += w * inL[p + 4][INDIM + k];
    acc3 += w * inL[p + 6][INDIM + k];
  }
  float bj = bo[j], bmj = ws[OFF_BMO + j];
  {
    float a;
    a = acc0 + bj + inL[p + 0][K2DIM] * bmj;
    hL[p + 0][j] = 0.5f * a * (1.f + erff(a * 0.70710678118654752f));
    a = acc1 + bj + inL[p + 2][K2DIM] * bmj;
    hL[p + 2][j] = 0.5f * a * (1.f + erff(a * 0.70710678118654752f));
    a = acc2 + bj + inL[p + 4][K2DIM] * bmj;
    hL[p + 4][j] = 0.5f * a * (1.f + erff(a * 0.70710678118654752f));
    a = acc3 + bj + inL[p + 6][K2DIM] * bmj;
    hL[p + 6][j] = 0.5f * a * (1.f + erff(a * 0.70710678118654752f));
  }
  __syncthreads();

  for (int t = 0; t < 2; ++t) {
    int n = wv * 2 + t;
    float v0 = hL[n][lane], v1 = hL[n][64 + lane];
    float s = v0 + v1, s2 = v0 * v0 + v1 * v1;
    for (int off = 32; off; off >>= 1) {
      s  += __shfl_xor(s, off);
      s2 += __shfl_xor(s2, off);
    }
    float mu = s * (1.f / OD);
    float var = s2 * (1.f / OD) - mu * mu;
    float rstd = rsqrtf(var + 1e-5f);
    long nn = node0 + n;
    out[nn * OD + lane]      = (v0 - mu) * rstd * lng[lane] + lnb[lane];
    out[nn * OD + 64 + lane] = (v1 - mu) * rstd * lng[64 + lane] + lnb[64 + lane];
  }
}

extern "C" void kernel_launch(void* const* d_in, const int* in_sizes, int n_in,
                              void* d_out, int out_size, void* d_ws, size_t ws_size,
                              hipStream_t stream) {
  const float* x   = (const float*)d_in[0];
  const int*   ei  = (const int*)d_in[1];
  const float* ef  = (const float*)d_in[2];
  const float* td  = (const float*)d_in[3];
  const float* gm  = (const float*)d_in[4];
  const float* Wm  = (const float*)d_in[5];
  const float* bm  = (const float*)d_in[6];
  const float* Wa  = (const float*)d_in[7];
  const float* ba  = (const float*)d_in[8];
  const float* Wo  = (const float*)d_in[9];
  const float* bo  = (const float*)d_in[10];
  const float* lng = (const float*)d_in[11];
  const float* lnb = (const float*)d_in[12];
  float* ws = (float*)d_ws;
  float* out = (float*)d_out;
  if (ws_size < (size_t)WS_FLOATS * 4) return;

  hipMemsetAsync(ws + OFF_CNT, 0, 50000 * 4, stream);
  hipMemsetAsync(ws + OFF_DENOM, 0, 64, stream);

  k0_prep<<<INDIM + 1, 128, 0, stream>>>(Wm, bm, Wa, ba, Wo, gm, ws);
  k0b_nodeproj<<<12500, 256, 0, stream>>>(x, Wa, ws);
  k1_logits<<<1024, 256, 0, stream>>>(ei, ef, td, ws);
  k_scan<<<1, 256, 0, stream>>>(ws);
  k_fill<<<1024, 256, 0, stream>>>(ei, ws);
  k4_out<<<N_NODES / 8, 256, 0, stream>>>(x, ei, ef, td, Wo, bo, lng, lnb, ws, out);
}

// Round 3
// 455.271 us; speedup vs baseline: 2.6934x; 1.3095x over previous
//
#include <hip/hip_runtime.h>
#include <math.h>

#define N_NODES 50000
#define N_EDGES 800000
#define ND 128
#define ED 64
#define TD 16
#define OD 128
#define NH 4
#define INDIM 208   // ND+ED+TD
#define K2DIM 336   // INDIM + ND
#define KPAD 352    // K2DIM padded to 11*32
#define WTPITCH 360 // Wt row pitch in bf16 (bank-spread)
#define NPAD 50048  // nodes padded to 64

// workspace layout (float offsets). A (bf16, NPAD x KPAD) aliases EXPL:
// k1 writes EXPL -> k_fill consumes EXPL -> k4a overwrites region with A -> k4b reads A.
#define OFF_A      0ll           // 50048*352 ushort = 8,808,448 floats
#define OFF_EXPL   0ll           // 800000 float4 = 3,200,000 floats (alias of A)
#define OFF_PERM   8808448ll     // 800000 uint4 = 3,200,000 floats
#define OFF_DENOM  12008448ll    // 16
#define OFF_SPG    12008464ll    // 16
#define OFF_WFUSE  12008480ll    // 832
#define OFF_BFUSE  12009312ll    // 16
#define OFF_BMO    12009328ll    // 128
#define OFF_XS4    12009456ll    // 200000
#define OFF_XD4    12209456ll    // 200000
#define OFF_CNT    12409456ll    // 50000 ints
#define OFF_START  12459456ll    // 50016 ints
#define OFF_CURSOR 12509472ll    // 50000 ints
#define OFF_SW     12559472ll    // 50048 floats
#define OFF_WT     12609520ll    // 128*360 ushort = 23040 floats
#define WS_FLOATS  12632560ll

typedef __attribute__((ext_vector_type(8))) short short8v;
typedef __attribute__((ext_vector_type(4))) float f32x4;

__device__ inline unsigned short f2bf(float f) {
  unsigned u = __float_as_uint(f);
  unsigned r = (u + 0x7fffu + ((u >> 16) & 1u)) >> 16;
  return (unsigned short)r;
}

// ---------------- K0: fold weights + build bf16 Wt ----------------
// Wt[col][k] (transposed, pitch 360): k<208 -> (Wm@Wo_top)[k][col]; 208..335 -> Wo[128+k-208][col]; pad 0.
// Wfuse = Wm @ Wa_top (208x4), bfuse = bm@Wa_top + ba, bmj = bm@Wo_top, spg = softplus(gammas)
__global__ void k0_prep(const float* __restrict__ Wm, const float* __restrict__ bm,
                        const float* __restrict__ Wa, const float* __restrict__ ba,
                        const float* __restrict__ Wo, const float* __restrict__ gammas,
                        float* __restrict__ ws) {
  int b = blockIdx.x, j = threadIdx.x;
  unsigned short* Wt = (unsigned short*)(ws + OFF_WT);
  if (b < INDIM) {
    float acc = 0.f;
    for (int m = 0; m < OD; ++m) acc += Wm[b * OD + m] * Wo[m * OD + j];
    Wt[j * WTPITCH + b] = f2bf(acc);
    if (j < NH) {
      float a = 0.f;
      for (int m = 0; m < OD; ++m) a += Wm[b * OD + m] * Wa[m * NH + j];
      ws[OFF_WFUSE + (long)b * NH + j] = a;
    }
  } else if (b < K2DIM) {
    Wt[j * WTPITCH + b] = f2bf(Wo[(OD + b - INDIM) * OD + j]);
  } else {
    if (j < TD) ws[OFF_SPG + j] = log1pf(expf(gammas[j]));
    if (j < NH) {
      float a = ba[j];
      for (int m = 0; m < OD; ++m) a += bm[m] * Wa[m * NH + j];
      ws[OFF_BFUSE + j] = a;
    }
    float a2 = 0.f;
    for (int m = 0; m < OD; ++m) a2 += bm[m] * Wo[m * OD + j];
    ws[OFF_BMO + j] = a2;
    for (int p = K2DIM; p < KPAD; ++p) Wt[j * WTPITCH + p] = 0;
  }
}

// ---------------- K0b: per-node 4-dim projections ----------------
__global__ __launch_bounds__(256) void k0b_nodeproj(
    const float* __restrict__ x, const float* __restrict__ Wa,
    float* __restrict__ ws) {
  __shared__ float wf[ND * NH];
  __shared__ float wab[ND * NH];
  int tid = threadIdx.x;
  for (int i = tid; i < ND * NH; i += 256) { wf[i] = ws[OFF_WFUSE + i]; wab[i] = Wa[ND * NH + i]; }
  __syncthreads();
  int lane = tid & 63, wv = tid >> 6;
  long n = (long)blockIdx.x * 4 + wv;
  if (n >= N_NODES) return;
  float v0 = x[n * ND + lane], v1 = x[n * ND + 64 + lane];
  float s0, s1, s2, s3, d0, d1, d2, d3;
  s0 = v0 * wf[lane * 4 + 0] + v1 * wf[(64 + lane) * 4 + 0];
  s1 = v0 * wf[lane * 4 + 1] + v1 * wf[(64 + lane) * 4 + 1];
  s2 = v0 * wf[lane * 4 + 2] + v1 * wf[(64 + lane) * 4 + 2];
  s3 = v0 * wf[lane * 4 + 3] + v1 * wf[(64 + lane) * 4 + 3];
  d0 = v0 * wab[lane * 4 + 0] + v1 * wab[(64 + lane) * 4 + 0];
  d1 = v0 * wab[lane * 4 + 1] + v1 * wab[(64 + lane) * 4 + 1];
  d2 = v0 * wab[lane * 4 + 2] + v1 * wab[(64 + lane) * 4 + 2];
  d3 = v0 * wab[lane * 4 + 3] + v1 * wab[(64 + lane) * 4 + 3];
  for (int off = 32; off; off >>= 1) {
    s0 += __shfl_xor(s0, off); s1 += __shfl_xor(s1, off);
    s2 += __shfl_xor(s2, off); s3 += __shfl_xor(s3, off);
    d0 += __shfl_xor(d0, off); d1 += __shfl_xor(d1, off);
    d2 += __shfl_xor(d2, off); d3 += __shfl_xor(d3, off);
  }
  if (lane == 0) {
    reinterpret_cast<float4*>(ws + OFF_XS4)[n] = make_float4(s0, s1, s2, s3);
    reinterpret_cast<float4*>(ws + OFF_XD4)[n] = make_float4(d0, d1, d2, d3);
  }
}

// ---------------- K1: edge logits + exp + denominator + dst histogram ----------------
__global__ __launch_bounds__(256) void k1_logits(
    const int* __restrict__ ei, const float* __restrict__ ef,
    const float* __restrict__ td, float* __restrict__ ws) {
  __shared__ float wef[ED * NH];
  __shared__ float wte[TD * NH];
  __shared__ float bf[NH];
  __shared__ float spg[TD];
  __shared__ float part[NH];
  int tid = threadIdx.x;
  for (int i = tid; i < ED * NH; i += 256) wef[i] = ws[OFF_WFUSE + ND * NH + i];
  if (tid < TD * NH) wte[tid] = ws[OFF_WFUSE + (ND + ED) * NH + tid];
  if (tid < NH) { bf[tid] = ws[OFF_BFUSE + tid]; part[tid] = 0.f; }
  if (tid < TD) spg[tid] = ws[OFF_SPG + tid];
  __syncthreads();

  int r = tid & 15;
  long grp = ((long)blockIdx.x * 256 + tid) >> 4;
  long ngrp = ((long)gridDim.x * 256) >> 4;
  const float4* ef4 = reinterpret_cast<const float4*>(ef);
  float4* expl4 = reinterpret_cast<float4*>(ws + OFF_EXPL);
  const float4* xs4 = reinterpret_cast<const float4*>(ws + OFF_XS4);
  const float4* xd4 = reinterpret_cast<const float4*>(ws + OFF_XD4);
  int* cnt = reinterpret_cast<int*>(ws + OFF_CNT);
  float p0 = 0.f, p1 = 0.f, p2 = 0.f, p3 = 0.f;

  for (long e = grp; e < N_EDGES; e += ngrp) {
    float4 efv = ef4[e * 16 + r];
    const float* w0 = &wef[(4 * r) * 4];
    float a0 = efv.x * w0[0] + efv.y * w0[4] + efv.z * w0[8]  + efv.w * w0[12];
    float a1 = efv.x * w0[1] + efv.y * w0[5] + efv.z * w0[9]  + efv.w * w0[13];
    float a2 = efv.x * w0[2] + efv.y * w0[6] + efv.z * w0[10] + efv.w * w0[14];
    float a3 = efv.x * w0[3] + efv.y * w0[7] + efv.z * w0[11] + efv.w * w0[15];
    float dt = fmaxf(td[e], 0.f);
    float te = expf(-spg[r] * dt);
    a0 += te * wte[r * 4 + 0]; a1 += te * wte[r * 4 + 1];
    a2 += te * wte[r * 4 + 2]; a3 += te * wte[r * 4 + 3];
    for (int off = 8; off; off >>= 1) {
      a0 += __shfl_xor(a0, off); a1 += __shfl_xor(a1, off);
      a2 += __shfl_xor(a2, off); a3 += __shfl_xor(a3, off);
    }
    if (r == 0) {
      int s = ei[e], d = ei[N_EDGES + e];
      float4 xs = xs4[s], xd = xd4[d];
      float e0 = expf(a0 + xs.x + xd.x + bf[0]);
      float e1 = expf(a1 + xs.y + xd.y + bf[1]);
      float e2 = expf(a2 + xs.z + xd.z + bf[2]);
      float e3 = expf(a3 + xs.w + xd.w + bf[3]);
      expl4[e] = make_float4(e0, e1, e2, e3);
      p0 += e0; p1 += e1; p2 += e2; p3 += e3;
      atomicAdd(&cnt[d], 1);
    }
  }
  if ((tid & 15) == 0) {
    atomicAdd(&part[0], p0); atomicAdd(&part[1], p1);
    atomicAdd(&part[2], p2); atomicAdd(&part[3], p3);
  }
  __syncthreads();
  if (tid < NH) atomicAdd(&ws[OFF_DENOM + tid], part[tid]);
}

// ---------------- K2: exclusive scan (1024 threads) ----------------
__global__ __launch_bounds__(1024) void k_scan(float* __restrict__ ws) {
  const int* cnt = reinterpret_cast<const int*>(ws + OFF_CNT);
  int* startp = reinterpret_cast<int*>(ws + OFF_START);
  int* cursor = reinterpret_cast<int*>(ws + OFF_CURSOR);
  __shared__ int wsum[16];
  int tid = threadIdx.x;
  int lo = tid * 49, hi = min(lo + 49, N_NODES);
  int s = 0;
  for (int i = lo; i < hi; ++i) s += cnt[i];
  int lane = tid & 63, wv = tid >> 6;
  int sc = s;
  for (int off = 1; off < 64; off <<= 1) {
    int t = __shfl_up(sc, off);
    if (lane >= off) sc += t;
  }
  if (lane == 63) wsum[wv] = sc;
  __syncthreads();
  if (tid == 0) {
    int run = 0;
    for (int i = 0; i < 16; ++i) { int t = wsum[i]; wsum[i] = run; run += t; }
  }
  __syncthreads();
  int run = wsum[wv] + sc - s;   // exclusive prefix for this thread
  for (int i = lo; i < hi; ++i) { startp[i] = run; cursor[i] = run; run += cnt[i]; }
  if (tid == 1023) startp[N_NODES] = run;
}

// ---------------- K3: fill CSR perm with (src, edge, w, dt) ----------------
__global__ __launch_bounds__(256) void k_fill(const int* __restrict__ ei,
                                              const float* __restrict__ td,
                                              float* __restrict__ ws) {
  __shared__ float inv[NH];
  int tid = threadIdx.x;
  if (tid < NH) inv[tid] = 0.25f / ws[OFF_DENOM + tid];
  __syncthreads();
  const float4* expl4 = reinterpret_cast<const float4*>(ws + OFF_EXPL);
  int* cursor = reinterpret_cast<int*>(ws + OFF_CURSOR);
  uint4* perm = reinterpret_cast<uint4*>(ws + OFF_PERM);
  for (long e = (long)blockIdx.x * 256 + tid; e < N_EDGES; e += (long)gridDim.x * 256) {
    int s = ei[e], d = ei[N_EDGES + e];
    float4 ev = expl4[e];
    float w = ev.x * inv[0] + ev.y * inv[1] + ev.z * inv[2] + ev.w * inv[3];
    float dt = fmaxf(td[e], 0.f);
    int pos = atomicAdd(&cursor[d], 1);
    perm[pos] = make_uint4((unsigned)s, (unsigned)e, __float_as_uint(w), __float_as_uint(dt));
  }
}

// ---------------- K4a: CSR aggregation -> bf16 A rows + sum_w ----------------
__global__ __launch_bounds__(256) void k4a_agg(
    const float* __restrict__ x, const float* __restrict__ ef,
    float* __restrict__ ws) {
  __shared__ float spg_s[TD];
  int tid = threadIdx.x;
  if (tid < TD) spg_s[tid] = ws[OFF_SPG + tid];
  __syncthreads();
  int lane = tid & 63;
  long wid = (long)blockIdx.x * 4 + (tid >> 6);
  long nw = (long)gridDim.x * 4;
  const int* start = reinterpret_cast<const int*>(ws + OFF_START);
  const uint4* perm = reinterpret_cast<const uint4*>(ws + OFF_PERM);
  unsigned short* A = (unsigned short*)(ws + OFF_A);
  float spg_l = spg_s[lane & 15];

  for (long n = wid; n < N_NODES; n += nw) {
    int i0 = start[n], i1 = start[n + 1];
    float a0 = 0.f, a1 = 0.f, a2 = 0.f, a3 = 0.f, asw = 0.f;
    for (int base = i0; base < i1; base += 64) {
      int m = min(64, i1 - base);
      uint4 pk = make_uint4(0u, 0u, 0u, 0u);
      if (lane < m) pk = perm[base + lane];
      for (int j = 0; j < m; ++j) {
        int s  = __shfl((int)pk.x, j);
        int e  = __shfl((int)pk.y, j);
        float w  = __uint_as_float(__shfl((int)pk.z, j));
        float dt = __uint_as_float(__shfl((int)pk.w, j));
        a0 += w * x[(long)s * ND + lane];
        a1 += w * x[(long)s * ND + 64 + lane];
        a2 += w * ef[(long)e * ED + lane];
        a3 += w * __expf(-spg_l * dt);
        asw += w;
      }
    }
    unsigned short* Ar = A + n * KPAD;
    float xv0 = x[n * ND + lane], xv1 = x[n * ND + 64 + lane];
    Ar[lane] = f2bf(a0);
    Ar[64 + lane] = f2bf(a1);
    Ar[128 + lane] = f2bf(a2);
    if (lane < TD) Ar[192 + lane] = f2bf(a3);
    Ar[INDIM + lane] = f2bf(xv0);
    Ar[INDIM + 64 + lane] = f2bf(xv1);
    if (lane < 16) Ar[K2DIM + lane] = 0;
    if (lane == 0) ws[OFF_SW + n] = asw;
  }
}

// ---------------- K4b: MFMA bf16 GEMM (NPAD x KPAD @ KPAD x 128) + GELU + LN ----------------
__global__ __launch_bounds__(256) void k4b_mlp(
    const float* __restrict__ bo, const float* __restrict__ lng,
    const float* __restrict__ lnb, const float* __restrict__ ws,
    float* __restrict__ out) {
  __shared__ unsigned short wt[128 * WTPITCH];  // 90 KB, transposed W, bank-spread pitch
  __shared__ float tbl[512];                    // bo | bmj | lng | lnb
  int tid = threadIdx.x;
  {
    const unsigned* wg = (const unsigned*)(ws + OFF_WT);
    unsigned* wl = (unsigned*)wt;
    for (int i = tid; i < 128 * WTPITCH / 2; i += 256) wl[i] = wg[i];
    if (tid < 128) {
      tbl[tid] = bo[tid];
      tbl[128 + tid] = ws[OFF_BMO + tid];
      tbl[256 + tid] = lng[tid];
      tbl[384 + tid] = lnb[tid];
    }
  }
  __syncthreads();

  int lane = tid & 63, wv = tid >> 6;
  int c0 = lane & 15, grp = lane >> 4;
  long n0 = (long)blockIdx.x * 64 + (long)wv * 16;
  const unsigned short* A = (const unsigned short*)(ws + OFF_A);
  const unsigned short* Arow = A + (n0 + c0) * KPAD;

  f32x4 acc[8];
#pragma unroll
  for (int t = 0; t < 8; ++t) acc[t] = (f32x4){0.f, 0.f, 0.f, 0.f};

#pragma unroll
  for (int kt = 0; kt < 11; ++kt) {
    short8v afrag = *reinterpret_cast<const short8v*>(Arow + kt * 32 + grp * 8);
#pragma unroll
    for (int t = 0; t < 8; ++t) {
      short8v bfrag = *reinterpret_cast<const short8v*>(&wt[(t * 16 + c0) * WTPITCH + kt * 32 + grp * 8]);
      acc[t] = __builtin_amdgcn_mfma_f32_16x16x32_bf16(afrag, bfrag, acc[t], 0, 0, 0);
    }
  }

  const float* swp = ws + OFF_SW;
  float res[4][8];
#pragma unroll
  for (int r = 0; r < 4; ++r) {
    long row = n0 + grp * 4 + r;
    float sw = swp[row];
    float s = 0.f, s2 = 0.f;
#pragma unroll
    for (int t = 0; t < 8; ++t) {
      int col = c0 + 16 * t;
      float a = acc[t][r] + tbl[col] + sw * tbl[128 + col];
      float h = 0.5f * a * (1.f + erff(a * 0.70710678118654752f));
      res[r][t] = h;
      s += h; s2 += h * h;
    }
    s += __shfl_xor(s, 1);  s2 += __shfl_xor(s2, 1);
    s += __shfl_xor(s, 2);  s2 += __shfl_xor(s2, 2);
    s += __shfl_xor(s, 4);  s2 += __shfl_xor(s2, 4);
    s += __shfl_xor(s, 8);  s2 += __shfl_xor(s2, 8);
    float mu = s * (1.f / 128.f);
    float var = s2 * (1.f / 128.f) - mu * mu;
    float rstd = rsqrtf(var + 1e-5f);
    if (row < N_NODES) {
      float* op = out + row * OD;
#pragma unroll
      for (int t = 0; t < 8; ++t) {
        int col = c0 + 16 * t;
        op[col] = (res[r][t] - mu) * rstd * tbl[256 + col] + tbl[384 + col];
      }
    }
  }
}

extern "C" void kernel_launch(void* const* d_in, const int* in_sizes, int n_in,
                              void* d_out, int out_size, void* d_ws, size_t ws_size,
                              hipStream_t stream) {
  const float* x   = (const float*)d_in[0];
  const int*   ei  = (const int*)d_in[1];
  const float* ef  = (const float*)d_in[2];
  const float* td  = (const float*)d_in[3];
  const float* gm  = (const float*)d_in[4];
  const float* Wm  = (const float*)d_in[5];
  const float* bm  = (const float*)d_in[6];
  const float* Wa  = (const float*)d_in[7];
  const float* ba  = (const float*)d_in[8];
  const float* Wo  = (const float*)d_in[9];
  const float* bo  = (const float*)d_in[10];
  const float* lng = (const float*)d_in[11];
  const float* lnb = (const float*)d_in[12];
  float* ws = (float*)d_ws;
  float* out = (float*)d_out;
  if (ws_size < (size_t)WS_FLOATS * 4) return;

  hipMemsetAsync(ws + OFF_CNT, 0, 50000 * 4, stream);
  hipMemsetAsync(ws + OFF_DENOM, 0, 64, stream);

  k0_prep<<<K2DIM + 1, 128, 0, stream>>>(Wm, bm, Wa, ba, Wo, gm, ws);
  k0b_nodeproj<<<12500, 256, 0, stream>>>(x, Wa, ws);
  k1_logits<<<1024, 256, 0, stream>>>(ei, ef, td, ws);
  k_scan<<<1, 1024, 0, stream>>>(ws);
  k_fill<<<1024, 256, 0, stream>>>(ei, td, ws);
  k4a_agg<<<2048, 256, 0, stream>>>(x, ef, ws);
  k4b_mlp<<<(NPAD / 64), 256, 0, stream>>>(bo, lng, lnb, ws, out);
}

// Round 4
// 432.008 us; speedup vs baseline: 2.8384x; 1.0538x over previous
//
#include <hip/hip_runtime.h>
#include <math.h>

#define N_NODES 50000
#define N_EDGES 800000
#define ND 128
#define ED 64
#define TD 16
#define OD 128
#define NH 4
#define INDIM 208   // ND+ED+TD
#define K2DIM 336   // INDIM + ND
#define KPAD 352    // K2DIM padded to 11*32
#define WTPITCH 360 // Wt row pitch in bf16 (bank-spread)
#define NPAD 50048  // nodes padded to 64

// workspace layout (float offsets). A (bf16, NPAD x KPAD) aliases EXPL:
// k1 writes EXPL -> k_fill consumes EXPL -> k4a overwrites region with A -> k4b reads A.
#define OFF_A      0ll           // 50048*352 ushort = 8,808,448 floats
#define OFF_EXPL   0ll           // 800000 float4 = 3,200,000 floats (alias of A)
#define OFF_PERM   8808448ll     // 800000 uint4 = 3,200,000 floats
#define OFF_DENOM  12008448ll    // 16
#define OFF_SPG    12008464ll    // 16
#define OFF_WFUSE  12008480ll    // 832
#define OFF_BFUSE  12009312ll    // 16
#define OFF_BMO    12009328ll    // 128
#define OFF_XS4    12009456ll    // 200000
#define OFF_XD4    12209456ll    // 200000
#define OFF_CNT    12409456ll    // 50000 ints
#define OFF_START  12459456ll    // 50016 ints
#define OFF_CURSOR 12509472ll    // 50000 ints
#define OFF_SW     12559472ll    // 50048 floats
#define OFF_WT     12609520ll    // 128*360 ushort = 23040 floats
#define WS_FLOATS  12632560ll

typedef __attribute__((ext_vector_type(8))) short short8v;
typedef __attribute__((ext_vector_type(4))) float f32x4;

__device__ inline unsigned short f2bf(float f) {
  unsigned u = __float_as_uint(f);
  unsigned r = (u + 0x7fffu + ((u >> 16) & 1u)) >> 16;
  return (unsigned short)r;
}

// ---------------- K0: fold weights + build bf16 Wt ----------------
__global__ void k0_prep(const float* __restrict__ Wm, const float* __restrict__ bm,
                        const float* __restrict__ Wa, const float* __restrict__ ba,
                        const float* __restrict__ Wo, const float* __restrict__ gammas,
                        float* __restrict__ ws) {
  int b = blockIdx.x, j = threadIdx.x;
  unsigned short* Wt = (unsigned short*)(ws + OFF_WT);
  if (b < INDIM) {
    float acc = 0.f;
    for (int m = 0; m < OD; ++m) acc += Wm[b * OD + m] * Wo[m * OD + j];
    Wt[j * WTPITCH + b] = f2bf(acc);
    if (j < NH) {
      float a = 0.f;
      for (int m = 0; m < OD; ++m) a += Wm[b * OD + m] * Wa[m * NH + j];
      ws[OFF_WFUSE + (long)b * NH + j] = a;
    }
  } else if (b < K2DIM) {
    Wt[j * WTPITCH + b] = f2bf(Wo[(OD + b - INDIM) * OD + j]);
  } else {
    if (j < TD) ws[OFF_SPG + j] = log1pf(expf(gammas[j]));
    if (j < NH) {
      float a = ba[j];
      for (int m = 0; m < OD; ++m) a += bm[m] * Wa[m * NH + j];
      ws[OFF_BFUSE + j] = a;
    }
    float a2 = 0.f;
    for (int m = 0; m < OD; ++m) a2 += bm[m] * Wo[m * OD + j];
    ws[OFF_BMO + j] = a2;
    for (int p = K2DIM; p < KPAD; ++p) Wt[j * WTPITCH + p] = 0;
  }
}

// ---------------- K0b: per-node 4-dim projections ----------------
__global__ __launch_bounds__(256) void k0b_nodeproj(
    const float* __restrict__ x, const float* __restrict__ Wa,
    float* __restrict__ ws) {
  __shared__ float wf[ND * NH];
  __shared__ float wab[ND * NH];
  int tid = threadIdx.x;
  for (int i = tid; i < ND * NH; i += 256) { wf[i] = ws[OFF_WFUSE + i]; wab[i] = Wa[ND * NH + i]; }
  __syncthreads();
  int lane = tid & 63, wv = tid >> 6;
  long n = (long)blockIdx.x * 4 + wv;
  if (n >= N_NODES) return;
  float v0 = x[n * ND + lane], v1 = x[n * ND + 64 + lane];
  float s0, s1, s2, s3, d0, d1, d2, d3;
  s0 = v0 * wf[lane * 4 + 0] + v1 * wf[(64 + lane) * 4 + 0];
  s1 = v0 * wf[lane * 4 + 1] + v1 * wf[(64 + lane) * 4 + 1];
  s2 = v0 * wf[lane * 4 + 2] + v1 * wf[(64 + lane) * 4 + 2];
  s3 = v0 * wf[lane * 4 + 3] + v1 * wf[(64 + lane) * 4 + 3];
  d0 = v0 * wab[lane * 4 + 0] + v1 * wab[(64 + lane) * 4 + 0];
  d1 = v0 * wab[lane * 4 + 1] + v1 * wab[(64 + lane) * 4 + 1];
  d2 = v0 * wab[lane * 4 + 2] + v1 * wab[(64 + lane) * 4 + 2];
  d3 = v0 * wab[lane * 4 + 3] + v1 * wab[(64 + lane) * 4 + 3];
  for (int off = 32; off; off >>= 1) {
    s0 += __shfl_xor(s0, off); s1 += __shfl_xor(s1, off);
    s2 += __shfl_xor(s2, off); s3 += __shfl_xor(s3, off);
    d0 += __shfl_xor(d0, off); d1 += __shfl_xor(d1, off);
    d2 += __shfl_xor(d2, off); d3 += __shfl_xor(d3, off);
  }
  if (lane == 0) {
    reinterpret_cast<float4*>(ws + OFF_XS4)[n] = make_float4(s0, s1, s2, s3);
    reinterpret_cast<float4*>(ws + OFF_XD4)[n] = make_float4(d0, d1, d2, d3);
  }
}

// ---------------- K1: edge logits + exp + denominator + dst histogram ----------------
// 16 lanes per edge; head-rotated reduce; all loads issued up front.
__global__ __launch_bounds__(256) void k1_logits(
    const int* __restrict__ ei, const float* __restrict__ ef,
    const float* __restrict__ td, float* __restrict__ ws) {
  __shared__ float wef[ED * NH];
  __shared__ float wte[TD * NH];
  __shared__ float bf[NH];
  __shared__ float spg[TD];
  __shared__ float part[NH];
  int tid = threadIdx.x;
  for (int i = tid; i < ED * NH; i += 256) wef[i] = ws[OFF_WFUSE + ND * NH + i];
  if (tid < TD * NH) wte[tid] = ws[OFF_WFUSE + (ND + ED) * NH + tid];
  if (tid < NH) { bf[tid] = ws[OFF_BFUSE + tid]; part[tid] = 0.f; }
  if (tid < TD) spg[tid] = ws[OFF_SPG + tid];
  __syncthreads();

  int lane = tid & 63;
  int q = lane >> 4, r = lane & 15, h = r & 3;
  long wid = ((long)blockIdx.x * 256 + tid) >> 6;
  long stride = (long)gridDim.x * 16;  // (blocks*4 waves)*4 edges
  const float4* ef4 = reinterpret_cast<const float4*>(ef);
  float* expl = ws + OFF_EXPL;
  const float* xsf = ws + OFF_XS4;
  const float* xdf = ws + OFF_XD4;
  int* cnt = reinterpret_cast<int*>(ws + OFF_CNT);

  // hoist per-lane weights into registers (kills LDS bank conflicts in loop)
  float wr[16];
#pragma unroll
  for (int i = 0; i < 16; ++i) wr[i] = wef[16 * r + i];
  float spg_r = spg[r];
  float wt0 = wte[r * 4 + 0], wt1 = wte[r * 4 + 1];
  float wt2 = wte[r * 4 + 2], wt3 = wte[r * 4 + 3];
  float bfh = bf[h];
  float p = 0.f;

  for (long e = wid * 4 + q; e < N_EDGES; e += stride) {
    // independent loads up front (broadcast same-line within 16-lane group)
    int s = ei[e];
    int d = ei[N_EDGES + e];
    float dt = fmaxf(td[e], 0.f);
    float4 efv = ef4[e * 16 + r];
    float ls = xsf[4l * s + h];
    float ld = xdf[4l * d + h];
    float te = __expf(-spg_r * dt);
    float a0 = efv.x * wr[0] + efv.y * wr[4] + efv.z * wr[8]  + efv.w * wr[12] + te * wt0;
    float a1 = efv.x * wr[1] + efv.y * wr[5] + efv.z * wr[9]  + efv.w * wr[13] + te * wt1;
    float a2 = efv.x * wr[2] + efv.y * wr[6] + efv.z * wr[10] + efv.w * wr[14] + te * wt2;
    float a3 = efv.x * wr[3] + efv.y * wr[7] + efv.z * wr[11] + efv.w * wr[15] + te * wt3;
    // reduce over low 2 lane bits (all 4 heads)
    a0 += __shfl_xor(a0, 1); a1 += __shfl_xor(a1, 1);
    a2 += __shfl_xor(a2, 1); a3 += __shfl_xor(a3, 1);
    a0 += __shfl_xor(a0, 2); a1 += __shfl_xor(a1, 2);
    a2 += __shfl_xor(a2, 2); a3 += __shfl_xor(a3, 2);
    // head-rotate: lane picks head r&3
    float v = a0;
    v = (h == 1) ? a1 : v;
    v = (h == 2) ? a2 : v;
    v = (h == 3) ? a3 : v;
    // reduce across the four 4-lane blocks
    v += __shfl_xor(v, 4);
    v += __shfl_xor(v, 8);
    float ev = __expf(v + ls + ld + bfh);
    if (r < 4) { expl[e * 4 + r] = ev; p += ev; }
    if (r == 1) atomicAdd(&cnt[d], 1);
  }
  p += __shfl_xor(p, 16);
  p += __shfl_xor(p, 32);
  if (lane < 4) atomicAdd(&part[lane], p);
  __syncthreads();
  if (tid < NH) atomicAdd(&ws[OFF_DENOM + tid], part[tid]);
}

// ---------------- K2: exclusive scan (1024 threads) ----------------
__global__ __launch_bounds__(1024) void k_scan(float* __restrict__ ws) {
  const int* cnt = reinterpret_cast<const int*>(ws + OFF_CNT);
  int* startp = reinterpret_cast<int*>(ws + OFF_START);
  int* cursor = reinterpret_cast<int*>(ws + OFF_CURSOR);
  __shared__ int wsum[16];
  int tid = threadIdx.x;
  int lo = tid * 49, hi = min(lo + 49, N_NODES);
  int s = 0;
  for (int i = lo; i < hi; ++i) s += cnt[i];
  int lane = tid & 63, wv = tid >> 6;
  int sc = s;
  for (int off = 1; off < 64; off <<= 1) {
    int t = __shfl_up(sc, off);
    if (lane >= off) sc += t;
  }
  if (lane == 63) wsum[wv] = sc;
  __syncthreads();
  if (tid == 0) {
    int run = 0;
    for (int i = 0; i < 16; ++i) { int t = wsum[i]; wsum[i] = run; run += t; }
  }
  __syncthreads();
  int run = wsum[wv] + sc - s;   // exclusive prefix for this thread
  for (int i = lo; i < hi; ++i) { startp[i] = run; cursor[i] = run; run += cnt[i]; }
  if (tid == 1023) startp[N_NODES] = run;
}

// ---------------- K3: fill CSR perm with (src, edge, w, dt) ----------------
__global__ __launch_bounds__(256) void k_fill(const int* __restrict__ ei,
                                              const float* __restrict__ td,
                                              float* __restrict__ ws) {
  __shared__ float inv[NH];
  int tid = threadIdx.x;
  if (tid < NH) inv[tid] = 0.25f / ws[OFF_DENOM + tid];
  __syncthreads();
  const float4* expl4 = reinterpret_cast<const float4*>(ws + OFF_EXPL);
  int* cursor = reinterpret_cast<int*>(ws + OFF_CURSOR);
  uint4* perm = reinterpret_cast<uint4*>(ws + OFF_PERM);
  for (long e = (long)blockIdx.x * 256 + tid; e < N_EDGES; e += (long)gridDim.x * 256) {
    int s = ei[e], d = ei[N_EDGES + e];
    float4 ev = expl4[e];
    float w = ev.x * inv[0] + ev.y * inv[1] + ev.z * inv[2] + ev.w * inv[3];
    float dt = fmaxf(td[e], 0.f);
    int pos = atomicAdd(&cursor[d], 1);
    perm[pos] = make_uint4((unsigned)s, (unsigned)e, __float_as_uint(w), __float_as_uint(dt));
  }
}

// ---------------- K4a: CSR aggregation -> bf16 A rows + sum_w ----------------
__global__ __launch_bounds__(256) void k4a_agg(
    const float* __restrict__ x, const float* __restrict__ ef,
    float* __restrict__ ws) {
  __shared__ float spg_s[TD];
  int tid = threadIdx.x;
  if (tid < TD) spg_s[tid] = ws[OFF_SPG + tid];
  __syncthreads();
  int lane = tid & 63;
  long wid = (long)blockIdx.x * 4 + (tid >> 6);
  long nw = (long)gridDim.x * 4;
  const int* start = reinterpret_cast<const int*>(ws + OFF_START);
  const uint4* perm = reinterpret_cast<const uint4*>(ws + OFF_PERM);
  unsigned short* A = (unsigned short*)(ws + OFF_A);
  float spg_l = spg_s[lane & 15];

  for (long n = wid; n < N_NODES; n += nw) {
    int i0 = start[n], i1 = start[n + 1];
    float a0 = 0.f, a1 = 0.f, a2 = 0.f, a3 = 0.f, asw = 0.f;
    for (int base = i0; base < i1; base += 64) {
      int m = min(64, i1 - base);
      uint4 pk = make_uint4(0u, 0u, 0u, 0u);
      if (lane < m) pk = perm[base + lane];
      int j = 0;
      // 4-way unrolled: 12 independent gathers in flight
      for (; j + 4 <= m; j += 4) {
        int s4[4], e4[4]; float w4[4], dt4[4];
#pragma unroll
        for (int u = 0; u < 4; ++u) {
          s4[u]  = __shfl((int)pk.x, j + u);
          e4[u]  = __shfl((int)pk.y, j + u);
          w4[u]  = __uint_as_float(__shfl((int)pk.z, j + u));
          dt4[u] = __uint_as_float(__shfl((int)pk.w, j + u));
        }
        float xa[4], xb[4], ec[4];
#pragma unroll
        for (int u = 0; u < 4; ++u) {
          xa[u] = x[(long)s4[u] * ND + lane];
          xb[u] = x[(long)s4[u] * ND + 64 + lane];
          ec[u] = ef[(long)e4[u] * ED + lane];
        }
#pragma unroll
        for (int u = 0; u < 4; ++u) {
          a0 += w4[u] * xa[u];
          a1 += w4[u] * xb[u];
          a2 += w4[u] * ec[u];
          a3 += w4[u] * __expf(-spg_l * dt4[u]);
          asw += w4[u];
        }
      }
      for (; j < m; ++j) {
        int s  = __shfl((int)pk.x, j);
        int e  = __shfl((int)pk.y, j);
        float w  = __uint_as_float(__shfl((int)pk.z, j));
        float dt = __uint_as_float(__shfl((int)pk.w, j));
        a0 += w * x[(long)s * ND + lane];
        a1 += w * x[(long)s * ND + 64 + lane];
        a2 += w * ef[(long)e * ED + lane];
        a3 += w * __expf(-spg_l * dt);
        asw += w;
      }
    }
    unsigned short* Ar = A + n * KPAD;
    float xv0 = x[n * ND + lane], xv1 = x[n * ND + 64 + lane];
    Ar[lane] = f2bf(a0);
    Ar[64 + lane] = f2bf(a1);
    Ar[128 + lane] = f2bf(a2);
    if (lane < TD) Ar[192 + lane] = f2bf(a3);
    Ar[INDIM + lane] = f2bf(xv0);
    Ar[INDIM + 64 + lane] = f2bf(xv1);
    if (lane < 16) Ar[K2DIM + lane] = 0;
    if (lane == 0) ws[OFF_SW + n] = asw;
  }
}

// ---------------- K4b: MFMA bf16 GEMM (NPAD x KPAD @ KPAD x 128) + GELU + LN ----------------
__global__ __launch_bounds__(256) void k4b_mlp(
    const float* __restrict__ bo, const float* __restrict__ lng,
    const float* __restrict__ lnb, const float* __restrict__ ws,
    float* __restrict__ out) {
  __shared__ unsigned short wt[128 * WTPITCH];  // 90 KB, transposed W, bank-spread pitch
  __shared__ float tbl[512];                    // bo | bmj | lng | lnb
  int tid = threadIdx.x;
  {
    const unsigned* wg = (const unsigned*)(ws + OFF_WT);
    unsigned* wl = (unsigned*)wt;
    for (int i = tid; i < 128 * WTPITCH / 2; i += 256) wl[i] = wg[i];
    if (tid < 128) {
      tbl[tid] = bo[tid];
      tbl[128 + tid] = ws[OFF_BMO + tid];
      tbl[256 + tid] = lng[tid];
      tbl[384 + tid] = lnb[tid];
    }
  }
  __syncthreads();

  int lane = tid & 63, wv = tid >> 6;
  int c0 = lane & 15, grp = lane >> 4;
  long n0 = (long)blockIdx.x * 64 + (long)wv * 16;
  const unsigned short* A = (const unsigned short*)(ws + OFF_A);
  const unsigned short* Arow = A + (n0 + c0) * KPAD;

  f32x4 acc[8];
#pragma unroll
  for (int t = 0; t < 8; ++t) acc[t] = (f32x4){0.f, 0.f, 0.f, 0.f};

#pragma unroll
  for (int kt = 0; kt < 11; ++kt) {
    short8v afrag = *reinterpret_cast<const short8v*>(Arow + kt * 32 + grp * 8);
#pragma unroll
    for (int t = 0; t < 8; ++t) {
      short8v bfrag = *reinterpret_cast<const short8v*>(&wt[(t * 16 + c0) * WTPITCH + kt * 32 + grp * 8]);
      acc[t] = __builtin_amdgcn_mfma_f32_16x16x32_bf16(afrag, bfrag, acc[t], 0, 0, 0);
    }
  }

  const float* swp = ws + OFF_SW;
  float res[4][8];
#pragma unroll
  for (int r = 0; r < 4; ++r) {
    long row = n0 + grp * 4 + r;
    float sw = swp[row];
    float s = 0.f, s2 = 0.f;
#pragma unroll
    for (int t = 0; t < 8; ++t) {
      int col = c0 + 16 * t;
      float a = acc[t][r] + tbl[col] + sw * tbl[128 + col];
      float h = 0.5f * a * (1.f + erff(a * 0.70710678118654752f));
      res[r][t] = h;
      s += h; s2 += h * h;
    }
    s += __shfl_xor(s, 1);  s2 += __shfl_xor(s2, 1);
    s += __shfl_xor(s, 2);  s2 += __shfl_xor(s2, 2);
    s += __shfl_xor(s, 4);  s2 += __shfl_xor(s2, 4);
    s += __shfl_xor(s, 8);  s2 += __shfl_xor(s2, 8);
    float mu = s * (1.f / 128.f);
    float var = s2 * (1.f / 128.f) - mu * mu;
    float rstd = rsqrtf(var + 1e-5f);
    if (row < N_NODES) {
      float* op = out + row * OD;
#pragma unroll
      for (int t = 0; t < 8; ++t) {
        int col = c0 + 16 * t;
        op[col] = (res[r][t] - mu) * rstd * tbl[256 + col] + tbl[384 + col];
      }
    }
  }
}

extern "C" void kernel_launch(void* const* d_in, const int* in_sizes, int n_in,
                              void* d_out, int out_size, void* d_ws, size_t ws_size,
                              hipStream_t stream) {
  const float* x   = (const float*)d_in[0];
  const int*   ei  = (const int*)d_in[1];
  const float* ef  = (const float*)d_in[2];
  const float* td  = (const float*)d_in[3];
  const float* gm  = (const float*)d_in[4];
  const float* Wm  = (const float*)d_in[5];
  const float* bm  = (const float*)d_in[6];
  const float* Wa  = (const float*)d_in[7];
  const float* ba  = (const float*)d_in[8];
  const float* Wo  = (const float*)d_in[9];
  const float* bo  = (const float*)d_in[10];
  const float* lng = (const float*)d_in[11];
  const float* lnb = (const float*)d_in[12];
  float* ws = (float*)d_ws;
  float* out = (float*)d_out;
  if (ws_size < (size_t)WS_FLOATS * 4) return;

  hipMemsetAsync(ws + OFF_CNT, 0, 50000 * 4, stream);
  hipMemsetAsync(ws + OFF_DENOM, 0, 64, stream);

  k0_prep<<<K2DIM + 1, 128, 0, stream>>>(Wm, bm, Wa, ba, Wo, gm, ws);
  k0b_nodeproj<<<12500, 256, 0, stream>>>(x, Wa, ws);
  k1_logits<<<2048, 256, 0, stream>>>(ei, ef, td, ws);
  k_scan<<<1, 1024, 0, stream>>>(ws);
  k_fill<<<2048, 256, 0, stream>>>(ei, td, ws);
  k4a_agg<<<2048, 256, 0, stream>>>(x, ef, ws);
  k4b_mlp<<<(NPAD / 64), 256, 0, stream>>>(bo, lng, lnb, ws, out);
}